// Round 2
// baseline (347.652 us; speedup 1.0000x reference)
//
#include <hip/hip_runtime.h>

#define TOKENS 32768
#define DIN 1024
#define DOUT 1024
#define RANK 16
#define SCALE1 0.5f
#define SCALE2 1.0f

#define BM 128
#define BN 128
#define BK 32

typedef __bf16 bf16x8 __attribute__((ext_vector_type(8)));
typedef float f32x4 __attribute__((ext_vector_type(4)));

// Async global->LDS, 16B per lane. LDS dest is wave-uniform base + lane*16.
__device__ __forceinline__ void load_lds16(const void* gptr, void* lptr) {
    __builtin_amdgcn_global_load_lds(
        (__attribute__((address_space(1))) void*)gptr,
        (__attribute__((address_space(3))) void*)lptr, 16, 0, 0);
}

// ---------------------------------------------------------------------------
// Kernel 1: Weff = W + 0.5*B1@A1 + 1.0*B2@A2, cast to bf16.  [DOUT, DIN]
// ---------------------------------------------------------------------------
__global__ void weff_kernel(const float* __restrict__ W, const float* __restrict__ A1,
                            const float* __restrict__ B1, const float* __restrict__ A2,
                            const float* __restrict__ B2, __bf16* __restrict__ Weff) {
    int idx = blockIdx.x * blockDim.x + threadIdx.x;  // over DOUT*DIN
    int o = idx >> 10;
    int i = idx & 1023;
    float s1 = 0.f, s2 = 0.f;
#pragma unroll
    for (int r = 0; r < RANK; ++r) {
        s1 += B1[o * RANK + r] * A1[r * DIN + i];
        s2 += B2[o * RANK + r] * A2[r * DIN + i];
    }
    Weff[idx] = (__bf16)(W[idx] + SCALE1 * s1 + SCALE2 * s2);
}

// ---------------------------------------------------------------------------
// Kernel 2: x fp32 -> bf16, 8 elems/thread, 16B stores.
// ---------------------------------------------------------------------------
__global__ void cvt_x_kernel(const float* __restrict__ x, __bf16* __restrict__ xb) {
    int i = (blockIdx.x * blockDim.x + threadIdx.x) * 8;
    float4 a = *(const float4*)(x + i);
    float4 b = *(const float4*)(x + i + 4);
    bf16x8 v;
    v[0] = (__bf16)a.x; v[1] = (__bf16)a.y; v[2] = (__bf16)a.z; v[3] = (__bf16)a.w;
    v[4] = (__bf16)b.x; v[5] = (__bf16)b.y; v[6] = (__bf16)b.z; v[7] = (__bf16)b.w;
    *(bf16x8*)(xb + i) = v;
}

// ---------------------------------------------------------------------------
// Kernel 3: out[M,N] = A[M,K] @ Bw[N,K]^T + bias.  m97-style 128x128 tile.
//
// LDS bank-conflict fix (R1): logical 16B chunk c of row r is stored at
// physical chunk  c ^ ((r>>1)&3).  The staging write path (global_load_lds,
// lane l -> LDS offset l*16) realizes this by permuting the GLOBAL chunk each
// lane fetches (same 64B segment, coalescing unchanged); the fragment read
// XORs the chunk index. Quarter-wave then covers all 32 banks exactly twice
// (2-way = free) instead of 4x on half the banks.
// ---------------------------------------------------------------------------
__global__ __launch_bounds__(256) void gemm_bt_kernel(
    const __bf16* __restrict__ A,   // [TOKENS, DIN] bf16
    const __bf16* __restrict__ Bw,  // [DOUT, DIN] bf16
    const float* __restrict__ bias, float* __restrict__ C) {
    __shared__ __bf16 lsA[BM * BK];  // 8 KB, row stride BK, chunk-swizzled
    __shared__ __bf16 lsB[BN * BK];  // 8 KB

    const int tid = threadIdx.x;
    const int wave = tid >> 6;
    const int lane = tid & 63;
    const int m0 = blockIdx.y * BM;
    const int n0 = blockIdx.x * BN;
    const int wm = wave >> 1;  // 0..1
    const int wn = wave & 1;   // 0..1

    // Staging: lane l covers row l>>2 of a 16-row slab; fetches logical chunk
    // (l&3) ^ ((l>>3)&3) so it lands at physical chunk l&3 under the swizzle.
    const int lrow = lane >> 2;
    const int lcol = ((lane & 3) ^ ((lane >> 3) & 3)) * 8;  // element offset

    const __bf16* gA = A + (size_t)(m0 + wave * 32 + lrow) * DIN + lcol;
    const __bf16* gB = Bw + (size_t)(n0 + wave * 32 + lrow) * DIN + lcol;
    __bf16* lA0 = &lsA[(wave * 32) * BK];
    __bf16* lA1 = &lsA[(wave * 32 + 16) * BK];
    __bf16* lB0 = &lsB[(wave * 32) * BK];
    __bf16* lB1 = &lsB[(wave * 32 + 16) * BK];

    f32x4 acc[4][4];
#pragma unroll
    for (int i = 0; i < 4; ++i)
#pragma unroll
        for (int j = 0; j < 4; ++j) acc[i][j] = f32x4{0.f, 0.f, 0.f, 0.f};

    // Fragment addressing: A[m=lane&15][k=(lane>>4)*8+j].
    // Chunk index C = lane>>4, row fr = lane&15; physical chunk = C ^ ((fr>>1)&3).
    const int fr = lane & 15;
    const int fsw = (((lane >> 4) ^ ((lane >> 1) & 3))) * 8;  // swizzled elem offset

    for (int k0 = 0; k0 < DIN; k0 += BK) {
        load_lds16(gA + k0, lA0);
        load_lds16(gA + k0 + 16 * DIN, lA1);
        load_lds16(gB + k0, lB0);
        load_lds16(gB + k0 + 16 * DIN, lB1);
        __syncthreads();

        bf16x8 af[4], bfv[4];
#pragma unroll
        for (int t = 0; t < 4; ++t) {
            af[t] = *(const bf16x8*)&lsA[(wm * 64 + t * 16 + fr) * BK + fsw];
            bfv[t] = *(const bf16x8*)&lsB[(wn * 64 + t * 16 + fr) * BK + fsw];
        }
#pragma unroll
        for (int mt = 0; mt < 4; ++mt)
#pragma unroll
            for (int nt = 0; nt < 4; ++nt)
                acc[mt][nt] = __builtin_amdgcn_mfma_f32_16x16x32_bf16(
                    af[mt], bfv[nt], acc[mt][nt], 0, 0, 0);
        __syncthreads();
    }

    // Epilogue: C/D layout col = lane&15, row = (lane>>4)*4 + reg.
    const int rbase = (lane >> 4) * 4;
#pragma unroll
    for (int nt = 0; nt < 4; ++nt) {
        const int n = n0 + wn * 64 + nt * 16 + fr;
        const float bv = bias[n];
#pragma unroll
        for (int mt = 0; mt < 4; ++mt) {
            const int m = m0 + wm * 64 + mt * 16 + rbase;
            float* cp = C + (size_t)m * DOUT + n;
#pragma unroll
            for (int r = 0; r < 4; ++r) cp[(size_t)r * DOUT] = acc[mt][nt][r] + bv;
        }
    }
}

// ---------------------------------------------------------------------------
extern "C" void kernel_launch(void* const* d_in, const int* in_sizes, int n_in,
                              void* d_out, int out_size, void* d_ws, size_t ws_size,
                              hipStream_t stream) {
    const float* x  = (const float*)d_in[0];
    const float* W  = (const float*)d_in[1];
    const float* b  = (const float*)d_in[2];
    const float* A1 = (const float*)d_in[3];
    const float* B1 = (const float*)d_in[4];
    const float* A2 = (const float*)d_in[5];
    const float* B2 = (const float*)d_in[6];
    float* out = (float*)d_out;

    // Workspace: [x_bf16: 64 MB][Weff_bf16: 2 MB]
    __bf16* xb   = (__bf16*)d_ws;
    __bf16* Weff = (__bf16*)((char*)d_ws + (size_t)TOKENS * DIN * sizeof(__bf16));

    cvt_x_kernel<<<TOKENS * DIN / (256 * 8), 256, 0, stream>>>(x, xb);
    weff_kernel<<<DOUT * DIN / 256, 256, 0, stream>>>(W, A1, B1, A2, B2, Weff);
    // Grid: n-tiles fastest so the 8 n-blocks sharing an A-tile are adjacent in
    // dispatch order (A-tile L2 reuse); Weff (2 MB) stays resident in per-XCD L2.
    gemm_bt_kernel<<<dim3(DOUT / BN, TOKENS / BM), 256, 0, stream>>>(xb, Weff, b, out);
}

// Round 3
// 341.582 us; speedup vs baseline: 1.0178x; 1.0178x over previous
//
#include <hip/hip_runtime.h>

#define TOKENS 32768
#define DIN 1024
#define DOUT 1024
#define RANK 16
#define SCALE1 0.5f
#define SCALE2 1.0f

#define BM 128
#define BN 128
#define BK 32

typedef __bf16 bf16x8 __attribute__((ext_vector_type(8)));
typedef float f32x4 __attribute__((ext_vector_type(4)));

// Async global->LDS, 16B per lane. LDS dest is wave-uniform base + lane*16.
__device__ __forceinline__ void load_lds16(const void* gptr, void* lptr) {
    __builtin_amdgcn_global_load_lds(
        (__attribute__((address_space(1))) void*)gptr,
        (__attribute__((address_space(3))) void*)lptr, 16, 0, 0);
}

// ---------------------------------------------------------------------------
// Kernel 1: Weff = W + 0.5*B1@A1 + 1.0*B2@A2, cast to bf16.  [DOUT, DIN]
// ---------------------------------------------------------------------------
__global__ void weff_kernel(const float* __restrict__ W, const float* __restrict__ A1,
                            const float* __restrict__ B1, const float* __restrict__ A2,
                            const float* __restrict__ B2, __bf16* __restrict__ Weff) {
    int idx = blockIdx.x * blockDim.x + threadIdx.x;  // over DOUT*DIN
    int o = idx >> 10;
    int i = idx & 1023;
    float s1 = 0.f, s2 = 0.f;
#pragma unroll
    for (int r = 0; r < RANK; ++r) {
        s1 += B1[o * RANK + r] * A1[r * DIN + i];
        s2 += B2[o * RANK + r] * A2[r * DIN + i];
    }
    Weff[idx] = (__bf16)(W[idx] + SCALE1 * s1 + SCALE2 * s2);
}

// ---------------------------------------------------------------------------
// Kernel 2: x fp32 -> bf16, 8 elems/thread, 16B stores.
// ---------------------------------------------------------------------------
__global__ void cvt_x_kernel(const float* __restrict__ x, __bf16* __restrict__ xb) {
    int i = (blockIdx.x * blockDim.x + threadIdx.x) * 8;
    float4 a = *(const float4*)(x + i);
    float4 b = *(const float4*)(x + i + 4);
    bf16x8 v;
    v[0] = (__bf16)a.x; v[1] = (__bf16)a.y; v[2] = (__bf16)a.z; v[3] = (__bf16)a.w;
    v[4] = (__bf16)b.x; v[5] = (__bf16)b.y; v[6] = (__bf16)b.z; v[7] = (__bf16)b.w;
    *(bf16x8*)(xb + i) = v;
}

// ---------------------------------------------------------------------------
// Kernel 3: out[M,N] = A[M,K] @ Bw[N,K]^T + bias.  128x128 tile.
//
// R1: XOR chunk swizzle (phys chunk = log chunk ^ ((row>>1)&3)) -> 0 bank
//     conflicts (verified R2).
// R2: double-buffered LDS + cross-iteration prefetch. Stage tile k+1 AFTER
//     the barrier, compute tile k. One barrier/iter (was 2). The vmcnt(0)
//     drain at the next barrier now lands after a full compute phase of
//     in-flight time instead of exposing full memory latency every iter.
// ---------------------------------------------------------------------------
__global__ __launch_bounds__(256) void gemm_bt_kernel(
    const __bf16* __restrict__ A,   // [TOKENS, DIN] bf16
    const __bf16* __restrict__ Bw,  // [DOUT, DIN] bf16
    const float* __restrict__ bias, float* __restrict__ C) {
    __shared__ alignas(16) __bf16 lsA[2][BM * BK];  // 2 x 8 KB
    __shared__ alignas(16) __bf16 lsB[2][BN * BK];  // 2 x 8 KB

    const int tid = threadIdx.x;
    const int wave = tid >> 6;
    const int lane = tid & 63;
    const int m0 = blockIdx.y * BM;
    const int n0 = blockIdx.x * BN;
    const int wm = wave >> 1;  // 0..1
    const int wn = wave & 1;   // 0..1

    // Staging: lane l covers row l>>2 of a 16-row slab; fetches logical chunk
    // (l&3) ^ ((l>>3)&3) so it lands at physical chunk l&3 under the swizzle.
    const int lrow = lane >> 2;
    const int lcol = ((lane & 3) ^ ((lane >> 3) & 3)) * 8;  // element offset

    const __bf16* gA = A + (size_t)(m0 + wave * 32 + lrow) * DIN + lcol;
    const __bf16* gB = Bw + (size_t)(n0 + wave * 32 + lrow) * DIN + lcol;
    const int so0 = (wave * 32) * BK;        // LDS elem offset, slab rows 0-15
    const int so1 = (wave * 32 + 16) * BK;   // slab rows 16-31

    f32x4 acc[4][4];
#pragma unroll
    for (int i = 0; i < 4; ++i)
#pragma unroll
        for (int j = 0; j < 4; ++j) acc[i][j] = f32x4{0.f, 0.f, 0.f, 0.f};

    // Fragment addressing: A[m=lane&15][k=(lane>>4)*8+j].
    // Physical chunk = (lane>>4) ^ ((fr>>1)&3), fr = lane&15.
    const int fr = lane & 15;
    const int fsw = ((lane >> 4) ^ ((lane >> 1) & 3)) * 8;  // swizzled elem offset

    // Prologue: stage tile 0 into buffer 0.
    load_lds16(gA, &lsA[0][so0]);
    load_lds16(gA + 16 * DIN, &lsA[0][so1]);
    load_lds16(gB, &lsB[0][so0]);
    load_lds16(gB + 16 * DIN, &lsB[0][so1]);

    int cur = 0;
    for (int k0 = 0; k0 < DIN; k0 += BK) {
        __syncthreads();  // drains buf[cur] staging (in flight since last iter)

        if (k0 + BK < DIN) {  // prefetch next tile into the other buffer
            const int kn = k0 + BK;
            load_lds16(gA + kn, &lsA[cur ^ 1][so0]);
            load_lds16(gA + kn + 16 * DIN, &lsA[cur ^ 1][so1]);
            load_lds16(gB + kn, &lsB[cur ^ 1][so0]);
            load_lds16(gB + kn + 16 * DIN, &lsB[cur ^ 1][so1]);
        }

        bf16x8 af[4], bfv[4];
#pragma unroll
        for (int t = 0; t < 4; ++t) {
            af[t] = *(const bf16x8*)&lsA[cur][(wm * 64 + t * 16 + fr) * BK + fsw];
            bfv[t] = *(const bf16x8*)&lsB[cur][(wn * 64 + t * 16 + fr) * BK + fsw];
        }
#pragma unroll
        for (int mt = 0; mt < 4; ++mt)
#pragma unroll
            for (int nt = 0; nt < 4; ++nt)
                acc[mt][nt] = __builtin_amdgcn_mfma_f32_16x16x32_bf16(
                    af[mt], bfv[nt], acc[mt][nt], 0, 0, 0);
        cur ^= 1;
    }

    // Epilogue: C/D layout col = lane&15, row = (lane>>4)*4 + reg.
    const int rbase = (lane >> 4) * 4;
#pragma unroll
    for (int nt = 0; nt < 4; ++nt) {
        const int n = n0 + wn * 64 + nt * 16 + fr;
        const float bv = bias[n];
#pragma unroll
        for (int mt = 0; mt < 4; ++mt) {
            const int m = m0 + wm * 64 + mt * 16 + rbase;
            float* cp = C + (size_t)m * DOUT + n;
#pragma unroll
            for (int r = 0; r < 4; ++r) cp[(size_t)r * DOUT] = acc[mt][nt][r] + bv;
        }
    }
}

// ---------------------------------------------------------------------------
extern "C" void kernel_launch(void* const* d_in, const int* in_sizes, int n_in,
                              void* d_out, int out_size, void* d_ws, size_t ws_size,
                              hipStream_t stream) {
    const float* x  = (const float*)d_in[0];
    const float* W  = (const float*)d_in[1];
    const float* b  = (const float*)d_in[2];
    const float* A1 = (const float*)d_in[3];
    const float* B1 = (const float*)d_in[4];
    const float* A2 = (const float*)d_in[5];
    const float* B2 = (const float*)d_in[6];
    float* out = (float*)d_out;

    // Workspace: [x_bf16: 64 MB][Weff_bf16: 2 MB]
    __bf16* xb   = (__bf16*)d_ws;
    __bf16* Weff = (__bf16*)((char*)d_ws + (size_t)TOKENS * DIN * sizeof(__bf16));

    cvt_x_kernel<<<TOKENS * DIN / (256 * 8), 256, 0, stream>>>(x, xb);
    weff_kernel<<<DOUT * DIN / 256, 256, 0, stream>>>(W, A1, B1, A2, B2, Weff);
    // Grid: n-tiles fastest so the 8 n-blocks sharing an A-tile are adjacent in
    // dispatch order (A-tile L2 reuse); Weff (2 MB) stays resident in per-XCD L2.
    gemm_bt_kernel<<<dim3(DOUT / BN, TOKENS / BM), 256, 0, stream>>>(xb, Weff, b, out);
}